// Round 1
// baseline (874.904 us; speedup 1.0000x reference)
//
#include <hip/hip_runtime.h>

// BinaryCorrelationMatcher: B=4, H=480, W=640, TEMPLATE=21 (pad 10), SEARCH=9.
//
// VERIFIED reference model (R14): corr = flat forward-raster sequential f32
// sum over 441 taps of the FMA-contracted agreement:
//   agr = fma(p1, s2, fl( fl(1-p1) * fl(1-s2) ));  s = fl(s + agr)
// s2 = shifted p2 (0 outside image); OOB taps exact +0 no-ops.
// Winner = (max f32, min k) = lax.scan strict-> first-wins.
//
// R22: attack the LDS-b32 ceiling found in R21's counters (26.8 TB/s LDS
// traffic == the 44 B/cyc/CU ds_read_b32 rate; VALUBusy only 60%).
//  - Rowsum slab TRANSPOSED (column-major, CSTR=64 floats/col) with a 16B
//    block XOR swizzle  blk ^ ((c&7)^(((c>>3)&3)<<1))  -> phase2's vertical
//    21-window becomes 7x ds_read_b128 (was 27x ds_read_b32/thread).
//    Swizzle chosen so producer's 8 scattered b32 writes are 2-way (free)
//    and b128 reads spread evenly over all 8 bank quads.
//  - Phase2: 8 rows/thread on 128 threads (col=tid&31, rg=(tid>>5)&3),
//    STREAMING prefix-sum (P[i+21]-P[i]) so only ~13 of 28 loaded floats
//    are live at once. Prefix-diff rounding delta <= eps*|P| ~ 3.5e-5
//    << MARGIN/2 budget (pass1 is a selector; flagged pixels replayed).
//  - Candidate ks PACKED as u16 pairs (bkp[8][2]) + predicated sorted
//    insert: top-4 state = 48 regs (R20's unpacked 8x4 = 64 regs spilled).
//  - __launch_bounds__(256,3): est. live set ~140 VGPR; the (256,4) cap of
//    128 is what scratched R19/R20 (WRITE_SIZE 14.6->23/43 MB). LDS 36.3KB
//    still permits 4 blocks/CU if allocator lands <=128.
// Ping-pong slabs -> ONE barrier per offset (unchanged from R18).
// MARGIN 0.002 (R17): pass1-vs-ref sigma ~1.4e-4 (+3.5e-5); budget 1e-3.
// Flagged: normal -> front worklist (<=4 cands); deep -> back worklist
// (361-replay). Overflow -> sentinel in flow slots.
//
// Pass 2: normal entries 16/wave (lane quad, shfl_xor reduce); deep
// wave-per-entry; then overflow-gated sentinel scan (normally skipped).
//
// Confidence: clip(((boxsum(q)+Nvalid)/2)/441, 0, 1), f32 (threshold 0.02).

#define HH 480
#define WW 640
#define TH 32
#define TW 32
#define QROWS 52   // TH+20
#define PROWS 70   // TH+38
#define PCOLS 70   // TW+38
#define PSTR  71
#define CSTR  64   // floats per column of transposed rowsum slab (16 blocks)
#define MARGIN 0.002f
#define NPIX (4 * HH * WW)

__device__ __forceinline__ int sw_g(int c) {
  // column hash: low 3 bits of c XOR (c>>3)<<1 -> spreads bank quads for
  // both the per-j producer writes (2-way) and the 32-col b128 reads.
  return (c & 7) ^ (((c >> 3) & 3) << 1);
}
// float index of (col c, row r) in a transposed swizzled slab
__device__ __forceinline__ int swadr(int c, int r) {
  return c * CSTR + ((((r >> 2) ^ sw_g(c)) << 2) | (r & 3));
}

// Bit-exact replica: forward-raster sequential f32 sum of FMA-contracted taps.
__device__ __forceinline__ float replay_corr(const float* __restrict__ p1b,
                                             const float* __restrict__ p2b,
                                             int y, int x, int k) {
  int dy = k / 19 - 9, dx = k % 19 - 9;
  float s = 0.f;
  for (int u = 0; u < 21; ++u) {
    int yy = y - 10 + u;
    if (yy < 0 || yy >= HH) continue;  // +0 taps: exact no-ops
    int y2 = yy + dy;
    bool yok = (y2 >= 0 && y2 < HH);
    const float* r1 = p1b + yy * WW;
    const float* r2 = p2b + y2 * WW;
#pragma unroll
    for (int v = 0; v < 21; ++v) {
      int xx = x - 10 + v;
      if (xx < 0 || xx >= WW) continue;  // +0 tap: exact no-op
      float p = r1[xx];
      int x2 = xx + dx;
      float s2 = (yok && x2 >= 0 && x2 < WW) ? r2[x2] : 0.f;
      float t2 = __fmul_rn(__fsub_rn(1.f, p), __fsub_rn(1.f, s2));
      float agr = __fmaf_rn(p, s2, t2);
      s = __fadd_rn(s, agr);
    }
  }
  return s;
}

__global__ __launch_bounds__(256, 3)
void bcm_pass1(const float* __restrict__ p1, const float* __restrict__ p2,
               float* __restrict__ out, unsigned* __restrict__ wl,
               unsigned capE) {
  __shared__ float ps[PROWS * PSTR];
  __shared__ __align__(16) float rsbT[2][32 * CSTR];  // transposed slabs

  const int tid = threadIdx.x;
  const int b  = blockIdx.z;
  const int y0 = blockIdx.y * TH;
  const int x0 = blockIdx.x * TW;
  const float* p1b = p1 + b * HH * WW;
  const float* p2b = p2 + b * HH * WW;

  // stage p2 tile (halo 19) into LDS
  for (int i = tid; i < PROWS * PCOLS; i += 256) {
    int rr = i / PCOLS, cc = i - rr * PCOLS;
    int Y = y0 - 19 + rr, X = x0 - 19 + cc;
    float v = 0.f;
    if (Y >= 0 && Y < HH && X >= 0 && X < WW) v = p2b[Y * WW + X];
    ps[rr * PSTR + cc] = v;
  }

  // consumer mapping: 128 threads, 8 rows each
  const int col = tid & 31;
  const int rg  = (tid >> 5) & 3;
  const int r0c = rg * 8;
  const bool active2 = (tid < 128);

  // producer mapping: 208 threads, one q-row x 8 cols each
  const int prow_ = tid >> 2;
  const int c0    = (tid & 3) * 8;
  const bool active1 = (prow_ < QROWS);

  // precomputed swizzled offsets (offset-independent)
  int roff[7];
  {
    const int g  = sw_g(col);
    const int rb = r0c >> 2;  // 2*rg
#pragma unroll
    for (int m = 0; m < 7; ++m)
      roff[m] = col * CSTR + (((rb + m) ^ g) << 2);
  }
  int woff[8];
#pragma unroll
  for (int j = 0; j < 8; ++j) woff[j] = swadr(c0 + j, prow_);

  // q taps straight from global into registers (28 = 21 + 7 for 8 cols)
  float qreg[28];
  if (active1) {
    int Y = y0 - 10 + prow_;
    bool yok = (Y >= 0 && Y < HH);
    const float* qrow = p1b + Y * WW;
#pragma unroll
    for (int t = 0; t < 28; ++t) {
      int X = x0 - 10 + c0 + t;
      float v = 0.f;
      if (yok && X >= 0 && X < WW) v = 2.f * qrow[X] - 1.f;
      qreg[t] = v;
    }
  }
  __syncthreads();

  // top-4 candidates per output pixel (sorted descending, ks packed u16x2)
  float    bv[8][4];
  unsigned bkp[8][2];
#pragma unroll
  for (int i = 0; i < 8; ++i) {
#pragma unroll
    for (int t = 0; t < 4; ++t) bv[i][t] = -1e30f;
    bkp[i][0] = 0u; bkp[i][1] = 0u;
  }

  float preg[28];  // circular window of p taps
  int k = 0;
  for (int dy = -9; dy <= 9; ++dy) {
    const float* prowp = active1 ? &ps[(prow_ + dy + 9) * PSTR + c0] : ps;
    if (active1) {
#pragma unroll
      for (int t = 0; t < 28; ++t) preg[t] = prowp[t];
    }
#pragma unroll
    for (int dxi = 0; dxi < 19; ++dxi, ++k) {
      float* slab = rsbT[k & 1];
      if (active1) {
        float s = 0.f;
#pragma unroll
        for (int t = 0; t < 21; ++t) s += qreg[t] * preg[(dxi + t) % 28];
        float rs[8];
        rs[0] = s;
#pragma unroll
        for (int j = 1; j < 8; ++j) {
          s += qreg[j + 20] * preg[(dxi + j + 20) % 28]
             - qreg[j - 1] * preg[(dxi + j - 1) % 28];
          rs[j] = s;
        }
#pragma unroll
        for (int j = 0; j < 8; ++j) slab[woff[j]] = rs[j];
        if (dxi < 18) preg[dxi % 28] = prowp[dxi + 28];  // next tap into freed slot
      }
      __syncthreads();  // single barrier per offset (ping-pong slabs)
      if (active2) {
        const unsigned ck = (unsigned)k;
        float acc = 0.f, pfx[8];
#pragma unroll
        for (int m = 0; m < 7; ++m) {
          const float4 v = *(const float4*)&slab[roff[m]];
          const float vv[4] = {v.x, v.y, v.z, v.w};
#pragma unroll
          for (int q = 0; q < 4; ++q) {
            const int u = m * 4 + q;
            if (u < 8) pfx[u] = acc;
            acc += vv[q];
            if (u >= 20) {
              const int i = u - 20;
              const float cv = acc - pfx[i];  // 21-row vertical sum
              if (cv > bv[i][3]) {            // predicated sorted insert
                const bool g0 = cv > bv[i][0];
                const bool g1 = cv > bv[i][1];
                const bool g2 = cv > bv[i][2];
                bv[i][3] = g2 ? bv[i][2] : cv;
                bv[i][2] = g2 ? (g1 ? bv[i][1] : cv) : bv[i][2];
                bv[i][1] = g1 ? (g0 ? bv[i][0] : cv) : bv[i][1];
                bv[i][0] = g0 ? cv : bv[i][0];
                const unsigned lo = bkp[i][0], hi = bkp[i][1];
                const unsigned k0 = lo & 0xFFFFu, k1 = lo >> 16;
                const unsigned k2 = hi & 0xFFFFu;
                const unsigned k3n = g2 ? k2 : ck;
                const unsigned k2n = g2 ? (g1 ? k1 : ck) : k2;
                const unsigned k1n = g1 ? (g0 ? k0 : ck) : k1;
                const unsigned k0n = g0 ? ck : k0;
                bkp[i][0] = k0n | (k1n << 16);
                bkp[i][1] = k2n | (k3n << 16);
              }
            }
          }
        }
      }
    }
  }

  // Confidence: horizontal sums of q (reuse qreg), then vertical prefix sums
  __syncthreads();  // drain last slab read before reuse
  if (active1) {
    float s = 0.f;
#pragma unroll
    for (int t = 0; t < 21; ++t) s += qreg[t];
    float rs[8];
    rs[0] = s;
#pragma unroll
    for (int j = 1; j < 8; ++j) {
      s += qreg[j + 20] - qreg[j - 1];
      rs[j] = s;
    }
#pragma unroll
    for (int j = 0; j < 8; ++j) rsbT[0][woff[j]] = rs[j];
  }
  __syncthreads();

  unsigned* cntN = wl;
  unsigned* cntD = wl + 1;
  uint4* entries = (uint4*)(wl + 8);
  const unsigned capHalf = capE >> 1;
  const int confoff = 4 * 2 * HH * WW;
  if (active2) {
    float o[8];
    {
      float acc = 0.f, pfx[8];
#pragma unroll
      for (int m = 0; m < 7; ++m) {
        const float4 v = *(const float4*)&rsbT[0][roff[m]];
        const float vv[4] = {v.x, v.y, v.z, v.w};
#pragma unroll
        for (int q = 0; q < 4; ++q) {
          const int u = m * 4 + q;
          if (u < 8) pfx[u] = acc;
          acc += vv[q];
          if (u >= 20) o[u - 20] = acc - pfx[u - 20];
        }
      }
    }
#pragma unroll
    for (int i = 0; i < 8; ++i) {
      int y = y0 + r0c + i;
      int x = x0 + col;
      int ny = min(y + 10, HH - 1) - max(y - 10, 0) + 1;
      int nx = min(x + 10, WW - 1) - max(x - 10, 0) + 1;
      float c = (o[i] + (float)(ny * nx)) * (1.f / 882.f);
      float conf = fminf(fmaxf(c, 0.f), 1.f);

      int kk0 = (int)(bkp[i][0] & 0xFFFFu);
      int kk1 = (int)(bkp[i][0] >> 16);
      int kk2 = (int)(bkp[i][1] & 0xFFFFu);
      int kk3 = (int)(bkp[i][1] >> 16);
      float ofx = (float)(kk0 % 19 - 9);
      float ofy = (float)(kk0 / 19 - 9);

      if (bv[i][0] - bv[i][1] <= MARGIN) {
        int cand[4];
        int n = 1; cand[0] = kk0;
        cand[n++] = kk1;  // t=1 within margin iff outer condition holds
        if (bv[i][0] - bv[i][2] <= MARGIN) cand[n++] = kk2;
        if (bv[i][0] - bv[i][3] <= MARGIN) cand[n++] = kk3;
        bool deep = (bv[i][0] - bv[i][3] <= MARGIN);
        unsigned pix = (unsigned)((b * HH + y) * WW + x);
        bool stored = false;
        if (!deep) {
          unsigned slot = atomicAdd(cntN, 1u);
          if (slot < capHalf) {
            unsigned kk[4];
#pragma unroll
            for (int t = 0; t < 4; ++t)
              kk[t] = (t < n) ? (unsigned)cand[t] : 0xFFFFu;
            uint4 e;
            e.x = pix;
            e.y = kk[0] | (kk[1] << 16);
            e.z = kk[2] | (kk[3] << 16);
            e.w = 0u;
            entries[slot] = e;
            stored = true;
          }
        } else {
          unsigned ds = atomicAdd(cntD, 1u);
          if (ds < capHalf) {
            uint4 e; e.x = pix; e.y = 0u; e.z = 0u; e.w = 0u;
            entries[capE - 1 - ds] = e;
            stored = true;
          }
        }
        if (!stored) {
          // overflow fallback: sentinel-encode candidates into flow slots
          int c2 = (n > 2) ? cand[2] : cand[0];
          int c3 = (n > 3) ? cand[3] : cand[0];
          int dpf = deep ? 1 : 0;
          ofx = (float)(1000000 + cand[0] + 512 * cand[1]);
          ofy = (float)(c2 + 512 * c3 + 262144 * dpf);
        }
      }
      out[((b * 2 + 0) * HH + y) * WW + x] = ofx;
      out[((b * 2 + 1) * HH + y) * WW + x] = ofy;
      out[confoff + (b * HH + y) * WW + x] = conf;
    }
  }
}

// Normal entries: 16 per wave (lane quad per entry, shfl_xor reduce).
// Deep entries: one wave per entry, 361 offsets split across lanes.
// Then (only if the worklist overflowed) a grid-stride sentinel scan.
__global__ __launch_bounds__(256)
void bcm_pass2(const float* __restrict__ p1, const float* __restrict__ p2,
               float* __restrict__ out, const unsigned* __restrict__ wl,
               unsigned capE) {
  const unsigned capHalf = capE >> 1;
  unsigned rawN = wl[0], rawD = wl[1];
  unsigned nN = rawN > capHalf ? capHalf : rawN;
  unsigned nD = rawD > capHalf ? capHalf : rawD;
  const uint4* entries = (const uint4*)(wl + 8);
  const int lane = threadIdx.x & 63;
  unsigned wid = blockIdx.x * (blockDim.x >> 6) + (threadIdx.x >> 6);
  unsigned nw = gridDim.x * (blockDim.x >> 6);

  // normal entries
  for (unsigned base = wid * 16; base < nN; base += nw * 16) {
    unsigned e = base + (lane >> 2);
    int c = lane & 3;
    float wv = -1e30f;
    int   wk = 0x7FFF;
    unsigned pix = 0;
    bool valid = (e < nN);
    if (valid) {
      uint4 ent = entries[e];
      pix = ent.x;
      unsigned kc = (c == 0) ? (ent.y & 0xFFFFu) :
                    (c == 1) ? (ent.y >> 16) :
                    (c == 2) ? (ent.z & 0xFFFFu) : (ent.z >> 16);
      if (kc != 0xFFFFu) {
        int b = pix / (HH * WW);
        int r = pix - b * (HH * WW);
        int y = r / WW, x = r - y * WW;
        wv = replay_corr(p1 + b * HH * WW, p2 + b * HH * WW, y, x, (int)kc);
        wk = (int)kc;
      }
    }
#pragma unroll
    for (int d = 1; d <= 2; d <<= 1) {
      float ov = __shfl_xor(wv, d, 64);
      int   ok = __shfl_xor(wk, d, 64);
      if (ov > wv || (ov == wv && ok < wk)) { wv = ov; wk = ok; }
    }
    if (valid && c == 0) {
      int b = pix / (HH * WW);
      int r = pix - b * (HH * WW);
      int y = r / WW, x = r - y * WW;
      int fxi = (b * 2 * HH + y) * WW + x;
      out[fxi] = (float)(wk % 19 - 9);
      out[fxi + HH * WW] = (float)(wk / 19 - 9);
    }
  }

  // deep entries
  for (unsigned d = wid; d < nD; d += nw) {
    uint4 ent = entries[capE - 1 - d];
    unsigned pix = ent.x;
    int b = pix / (HH * WW);
    int r = pix - b * (HH * WW);
    int y = r / WW, x = r - y * WW;
    const float* p1b = p1 + b * HH * WW;
    const float* p2b = p2 + b * HH * WW;
    float wv = -1e30f;
    int   wk = 0x7FFF;
    for (int k = lane; k < 361; k += 64) {
      float s = replay_corr(p1b, p2b, y, x, k);
      if (s > wv || (s == wv && k < wk)) { wv = s; wk = k; }
    }
    for (int off = 32; off > 0; off >>= 1) {
      float ov = __shfl_down(wv, off, 64);
      int   ok = __shfl_down(wk, off, 64);
      if (ov > wv || (ov == wv && ok < wk)) { wv = ov; wk = ok; }
    }
    if (lane == 0) {
      int fxi = (b * 2 * HH + y) * WW + x;
      out[fxi] = (float)(wk % 19 - 9);
      out[fxi + HH * WW] = (float)(wk / 19 - 9);
    }
  }

  // sentinel cleanup — only if the worklist overflowed (normally skipped)
  if (rawN > capHalf || rawD > capHalf) {
    int stride = gridDim.x * blockDim.x;
    for (int idx = blockIdx.x * blockDim.x + threadIdx.x; idx < NPIX;
         idx += stride) {
      int b = idx / (HH * WW);
      int r = idx - b * (HH * WW);
      int fxi = b * 2 * HH * WW + r;
      float fx = out[fxi];
      if (fx < 500000.f) continue;  // not a sentinel
      int fyi = fxi + HH * WW;
      int p = (int)fx - 1000000;
      int q = (int)out[fyi];
      int deep = q >> 18;
      int kk[4] = {p & 511, p >> 9, q & 511, (q >> 9) & 511};
      int y = r / WW, x = r - y * WW;
      const float* p1b = p1 + b * HH * WW;
      const float* p2b = p2 + b * HH * WW;
      float wv = 0.f; int win = -1;
      if (deep) {
        for (int k = 0; k < 361; ++k) {
          float s = replay_corr(p1b, p2b, y, x, k);
          if (win < 0 || s > wv) { wv = s; win = k; }
        }
      } else {
        for (int c = 0; c < 4; ++c) {
          int k = kk[c];
          float s = replay_corr(p1b, p2b, y, x, k);
          if (win < 0 || s > wv || (s == wv && k < win)) { wv = s; win = k; }
        }
      }
      out[fxi] = (float)(win % 19 - 9);
      out[fyi] = (float)(win / 19 - 9);
    }
  }
}

extern "C" void kernel_launch(void* const* d_in, const int* in_sizes, int n_in,
                              void* d_out, int out_size, void* d_ws, size_t ws_size,
                              hipStream_t stream) {
  const float* p1 = (const float*)d_in[0];
  const float* p2 = (const float*)d_in[1];
  float* out = (float*)d_out;
  unsigned* wl = (unsigned*)d_ws;
  unsigned capE = (ws_size >= 64) ? (unsigned)((ws_size - 32) / 16) : 0u;
  hipMemsetAsync(d_ws, 0, 32, stream);  // worklist counters
  dim3 grid1(WW / TW, HH / TH, 4);
  bcm_pass1<<<grid1, dim3(256), 0, stream>>>(p1, p2, out, wl, capE);
  bcm_pass2<<<dim3(512), dim3(256), 0, stream>>>(p1, p2, out, wl, capE);
}

// Round 2
// 671.136 us; speedup vs baseline: 1.3036x; 1.3036x over previous
//
#include <hip/hip_runtime.h>

// BinaryCorrelationMatcher: B=4, H=480, W=640, TEMPLATE=21 (pad 10), SEARCH=9.
//
// VERIFIED reference model (R14): corr = flat forward-raster sequential f32
// sum over 441 taps of the FMA-contracted agreement:
//   agr = fma(p1, s2, fl( fl(1-p1) * fl(1-s2) ));  s = fl(s + agr)
// s2 = shifted p2 (0 outside image); OOB taps exact +0 no-ops.
// Winner = (max f32, min k) = lax.scan strict-> first-wins.
//
// R23 = R18/R21 structure + ROW-PAIR float2 rowsum slab.
//  R22 post-mortem: transposed+XOR-swizzled b128 slab -> 24.4M bank
//  conflicts (model wrong) AND 128-thread consumer doubled the serial
//  chain per barrier phase (VALUBusy 60->42). Reverted both.
//  R23 keeps R21's 256-thread consumer (4 rows/thread, col=tid&31) and
//  changes ONLY the slab: layout [26 row-pairs][stride 66] of float2
//  (rows 2r,2r+1 adjacent). Consumer reads its 24-row window as 12
//  ds_read_b64 (was 27 ds_read_b32): per 32-lane phase 2 accesses/bank
//  (same free class as R21's verified patterns, m136). Producer writes 8
//  scattered b32 (8B apart -> ds_write2_b32 fusable); bank = prow+16cq+2j
//  mod 32 = 2 lanes/bank, free. LDS cyc/block-offset ~704 -> ~440;
//  VALU (~540) becomes the binding pipe.
//  Vertical 21-sum via pair-sums: S0 = sum(pairs 0..9) + va.x, then
//  slide S1=S0-v0.x+va.y, S2=S1-v0.y+vb.x, S3=S2-v1.x+vb.y. Pairwise
//  association differs from R21's sequential sum but error is SMALLER;
//  pass1 is a selector (MARGIN replay), budget 1e-3 vs sigma ~1.4e-4.
// Ping-pong slabs -> ONE barrier per offset (unchanged).
// LDS: ps 19.9K + 2*6.9K = 33.6K -> 4 blocks/CU.
// MARGIN 0.002 (R17). Flagged: normal -> front worklist (<=4 cands);
// deep -> back worklist (361-replay). Overflow -> sentinel in flow slots.
//
// Pass 2: normal entries 16/wave (lane quad, shfl_xor reduce); deep
// wave-per-entry; then overflow-gated sentinel scan (normally skipped).
//
// Confidence: clip(((boxsum(q)+Nvalid)/2)/441, 0, 1), f32 (threshold 0.02).

#define HH 480
#define WW 640
#define TH 32
#define TW 32
#define QROWS 52   // TH+20 (= 26 row pairs)
#define PROWS 70   // TH+38
#define PCOLS 70   // TW+38
#define PSTR  71
#define PSTR2 66   // floats per row-pair (32 float2 cols + 2 pad floats)
#define MARGIN 0.002f
#define NPIX (4 * HH * WW)

// Bit-exact replica: forward-raster sequential f32 sum of FMA-contracted taps.
__device__ __forceinline__ float replay_corr(const float* __restrict__ p1b,
                                             const float* __restrict__ p2b,
                                             int y, int x, int k) {
  int dy = k / 19 - 9, dx = k % 19 - 9;
  float s = 0.f;
  for (int u = 0; u < 21; ++u) {
    int yy = y - 10 + u;
    if (yy < 0 || yy >= HH) continue;  // +0 taps: exact no-ops
    int y2 = yy + dy;
    bool yok = (y2 >= 0 && y2 < HH);
    const float* r1 = p1b + yy * WW;
    const float* r2 = p2b + y2 * WW;
#pragma unroll
    for (int v = 0; v < 21; ++v) {
      int xx = x - 10 + v;
      if (xx < 0 || xx >= WW) continue;  // +0 tap: exact no-op
      float p = r1[xx];
      int x2 = xx + dx;
      float s2 = (yok && x2 >= 0 && x2 < WW) ? r2[x2] : 0.f;
      float t2 = __fmul_rn(__fsub_rn(1.f, p), __fsub_rn(1.f, s2));
      float agr = __fmaf_rn(p, s2, t2);
      s = __fadd_rn(s, agr);
    }
  }
  return s;
}

__global__ __launch_bounds__(256, 4)
void bcm_pass1(const float* __restrict__ p1, const float* __restrict__ p2,
               float* __restrict__ out, unsigned* __restrict__ wl,
               unsigned capE) {
  __shared__ float ps[PROWS * PSTR];
  __shared__ __align__(16) float rsb0[26 * PSTR2];
  __shared__ __align__(16) float rsb1[26 * PSTR2];

  const int tid = threadIdx.x;
  const int b  = blockIdx.z;
  const int y0 = blockIdx.y * TH;
  const int x0 = blockIdx.x * TW;
  const float* p1b = p1 + b * HH * WW;
  const float* p2b = p2 + b * HH * WW;

  // stage p2 tile (halo 19) into LDS
  for (int i = tid; i < PROWS * PCOLS; i += 256) {
    int rr = i / PCOLS, cc = i - rr * PCOLS;
    int Y = y0 - 19 + rr, X = x0 - 19 + cc;
    float v = 0.f;
    if (Y >= 0 && Y < HH && X >= 0 && X < WW) v = p2b[Y * WW + X];
    ps[rr * PSTR + cc] = v;
  }

  const int col = tid & 31;
  const int r0  = (tid >> 5) * 4;
  const int prow_ = tid >> 2;
  const int c0    = (tid & 3) * 8;
  const bool active1 = (prow_ < QROWS);

  // producer write base: pair (prow_>>1), parity (prow_&1), col block 2*c0
  const int wbase = (prow_ >> 1) * PSTR2 + (prow_ & 1) + 2 * c0;
  // consumer read base (float index): pair r0/2, col -> float2
  const int rdoff = (r0 >> 1) * PSTR2 + 2 * col;

  // q taps straight from global into registers (28 = 21 + 7 for 8 cols)
  float qreg[28];
  if (active1) {
    int Y = y0 - 10 + prow_;
    bool yok = (Y >= 0 && Y < HH);
    const float* qrow = p1b + Y * WW;
#pragma unroll
    for (int t = 0; t < 28; ++t) {
      int X = x0 - 10 + c0 + t;
      float v = 0.f;
      if (yok && X >= 0 && X < WW) v = 2.f * qrow[X] - 1.f;
      qreg[t] = v;
    }
  }
  __syncthreads();

  // top-4 candidates per output pixel (sorted descending)
  float bv[4][4];
  int   bk[4][4];
#pragma unroll
  for (int j = 0; j < 4; ++j)
#pragma unroll
    for (int t = 0; t < 4; ++t) { bv[j][t] = -1e30f; bk[j][t] = 0; }

  float preg[28];  // circular window of p taps
  int k = 0;
  for (int dy = -9; dy <= 9; ++dy) {
    const float* prowp = active1 ? &ps[(prow_ + dy + 9) * PSTR + c0] : ps;
    if (active1) {
#pragma unroll
      for (int t = 0; t < 28; ++t) preg[t] = prowp[t];
    }
#pragma unroll
    for (int dxi = 0; dxi < 19; ++dxi, ++k) {
      float* slab = (k & 1) ? rsb1 : rsb0;
      if (active1) {
        float s = 0.f;
#pragma unroll
        for (int t = 0; t < 21; ++t) s += qreg[t] * preg[(dxi + t) % 28];
        float rs[8];
        rs[0] = s;
#pragma unroll
        for (int j = 1; j < 8; ++j) {
          s += qreg[j + 20] * preg[(dxi + j + 20) % 28]
             - qreg[j - 1] * preg[(dxi + j - 1) % 28];
          rs[j] = s;
        }
#pragma unroll
        for (int j = 0; j < 8; ++j) slab[wbase + 2 * j] = rs[j];
        if (dxi < 18) preg[dxi % 28] = prowp[dxi + 28];  // next tap into freed slot
      }
      __syncthreads();  // single barrier per offset (ping-pong slabs)
      {
        const float2* rd = (const float2*)(slab + rdoff);
        const float2 v0 = rd[0 * 33];
        const float2 v1 = rd[1 * 33];
        const float2 v2 = rd[2 * 33];
        const float2 v3 = rd[3 * 33];
        const float2 v4 = rd[4 * 33];
        const float2 v5 = rd[5 * 33];
        const float2 v6 = rd[6 * 33];
        const float2 v7 = rd[7 * 33];
        const float2 v8 = rd[8 * 33];
        const float2 v9 = rd[9 * 33];
        const float2 va = rd[10 * 33];
        const float2 vb = rd[11 * 33];
        float acc = (v0.x + v0.y) + (v1.x + v1.y);
        acc += (v2.x + v2.y) + (v3.x + v3.y);
        acc += (v4.x + v4.y) + (v5.x + v5.y);
        acc += (v6.x + v6.y) + (v7.x + v7.y);
        acc += (v8.x + v8.y) + (v9.x + v9.y);
        float sv[4];
        sv[0] = acc + va.x;                 // rows r0   .. r0+20
        sv[1] = sv[0] - v0.x + va.y;        // rows r0+1 .. r0+21
        sv[2] = sv[1] - v0.y + vb.x;        // rows r0+2 .. r0+22
        sv[3] = sv[2] - v1.x + vb.y;        // rows r0+3 .. r0+23
#pragma unroll
        for (int j = 0; j < 4; ++j) {
          float cv = sv[j];
          if (cv > bv[j][3]) {
            int ck = k;
#pragma unroll
            for (int t = 0; t < 4; ++t) {   // sorted-insert; strict >
              if (cv > bv[j][t]) {
                float tv = bv[j][t]; int tk = bk[j][t];
                bv[j][t] = cv; bk[j][t] = ck;
                cv = tv; ck = tk;
              }
            }
          }
        }
      }
    }
  }

  // Confidence: horizontal sums of q (reuse qreg), then vertical pair sums
  __syncthreads();  // drain last slab read before reuse
  if (active1) {
    float s = 0.f;
#pragma unroll
    for (int t = 0; t < 21; ++t) s += qreg[t];
    float rs[8];
    rs[0] = s;
#pragma unroll
    for (int j = 1; j < 8; ++j) {
      s += qreg[j + 20] - qreg[j - 1];
      rs[j] = s;
    }
#pragma unroll
    for (int j = 0; j < 8; ++j) rsb0[wbase + 2 * j] = rs[j];
  }
  __syncthreads();

  unsigned* cntN = wl;
  unsigned* cntD = wl + 1;
  uint4* entries = (uint4*)(wl + 8);
  const unsigned capHalf = capE >> 1;
  const int confoff = 4 * 2 * HH * WW;
  {
    float o[4];
    {
      const float2* rd = (const float2*)(rsb0 + rdoff);
      const float2 v0 = rd[0 * 33];
      const float2 v1 = rd[1 * 33];
      const float2 v2 = rd[2 * 33];
      const float2 v3 = rd[3 * 33];
      const float2 v4 = rd[4 * 33];
      const float2 v5 = rd[5 * 33];
      const float2 v6 = rd[6 * 33];
      const float2 v7 = rd[7 * 33];
      const float2 v8 = rd[8 * 33];
      const float2 v9 = rd[9 * 33];
      const float2 va = rd[10 * 33];
      const float2 vb = rd[11 * 33];
      float acc = (v0.x + v0.y) + (v1.x + v1.y);
      acc += (v2.x + v2.y) + (v3.x + v3.y);
      acc += (v4.x + v4.y) + (v5.x + v5.y);
      acc += (v6.x + v6.y) + (v7.x + v7.y);
      acc += (v8.x + v8.y) + (v9.x + v9.y);
      o[0] = acc + va.x;
      o[1] = o[0] - v0.x + va.y;
      o[2] = o[1] - v0.y + vb.x;
      o[3] = o[2] - v1.x + vb.y;
    }
#pragma unroll
    for (int j = 0; j < 4; ++j) {
      int y = y0 + r0 + j;
      int x = x0 + col;
      int ny = min(y + 10, HH - 1) - max(y - 10, 0) + 1;
      int nx = min(x + 10, WW - 1) - max(x - 10, 0) + 1;
      float c = (o[j] + (float)(ny * nx)) * (1.f / 882.f);
      float conf = fminf(fmaxf(c, 0.f), 1.f);

      int kwin = bk[j][0];
      float ofx = (float)(kwin % 19 - 9);
      float ofy = (float)(kwin / 19 - 9);

      if (bv[j][0] - bv[j][1] <= MARGIN) {
        int cand[4];
        int n = 1; cand[0] = bk[j][0];
#pragma unroll
        for (int t = 1; t < 4; ++t)
          if (bv[j][0] - bv[j][t] <= MARGIN) cand[n++] = bk[j][t];
        bool deep = (bv[j][0] - bv[j][3] <= MARGIN);
        unsigned pix = (unsigned)((b * HH + y) * WW + x);
        bool stored = false;
        if (!deep) {
          unsigned slot = atomicAdd(cntN, 1u);
          if (slot < capHalf) {
            unsigned kk[4];
#pragma unroll
            for (int t = 0; t < 4; ++t)
              kk[t] = (t < n) ? (unsigned)cand[t] : 0xFFFFu;
            uint4 e;
            e.x = pix;
            e.y = kk[0] | (kk[1] << 16);
            e.z = kk[2] | (kk[3] << 16);
            e.w = 0u;
            entries[slot] = e;
            stored = true;
          }
        } else {
          unsigned ds = atomicAdd(cntD, 1u);
          if (ds < capHalf) {
            uint4 e; e.x = pix; e.y = 0u; e.z = 0u; e.w = 0u;
            entries[capE - 1 - ds] = e;
            stored = true;
          }
        }
        if (!stored) {
          // overflow fallback: sentinel-encode candidates into flow slots
          int c2 = (n > 2) ? cand[2] : cand[0];
          int c3 = (n > 3) ? cand[3] : cand[0];
          int dpf = deep ? 1 : 0;
          ofx = (float)(1000000 + cand[0] + 512 * cand[1]);
          ofy = (float)(c2 + 512 * c3 + 262144 * dpf);
        }
      }
      out[((b * 2 + 0) * HH + y) * WW + x] = ofx;
      out[((b * 2 + 1) * HH + y) * WW + x] = ofy;
      out[confoff + (b * HH + y) * WW + x] = conf;
    }
  }
}

// Normal entries: 16 per wave (lane quad per entry, shfl_xor reduce).
// Deep entries: one wave per entry, 361 offsets split across lanes.
// Then (only if the worklist overflowed) a grid-stride sentinel scan.
__global__ __launch_bounds__(256)
void bcm_pass2(const float* __restrict__ p1, const float* __restrict__ p2,
               float* __restrict__ out, const unsigned* __restrict__ wl,
               unsigned capE) {
  const unsigned capHalf = capE >> 1;
  unsigned rawN = wl[0], rawD = wl[1];
  unsigned nN = rawN > capHalf ? capHalf : rawN;
  unsigned nD = rawD > capHalf ? capHalf : rawD;
  const uint4* entries = (const uint4*)(wl + 8);
  const int lane = threadIdx.x & 63;
  unsigned wid = blockIdx.x * (blockDim.x >> 6) + (threadIdx.x >> 6);
  unsigned nw = gridDim.x * (blockDim.x >> 6);

  // normal entries
  for (unsigned base = wid * 16; base < nN; base += nw * 16) {
    unsigned e = base + (lane >> 2);
    int c = lane & 3;
    float wv = -1e30f;
    int   wk = 0x7FFF;
    unsigned pix = 0;
    bool valid = (e < nN);
    if (valid) {
      uint4 ent = entries[e];
      pix = ent.x;
      unsigned kc = (c == 0) ? (ent.y & 0xFFFFu) :
                    (c == 1) ? (ent.y >> 16) :
                    (c == 2) ? (ent.z & 0xFFFFu) : (ent.z >> 16);
      if (kc != 0xFFFFu) {
        int b = pix / (HH * WW);
        int r = pix - b * (HH * WW);
        int y = r / WW, x = r - y * WW;
        wv = replay_corr(p1 + b * HH * WW, p2 + b * HH * WW, y, x, (int)kc);
        wk = (int)kc;
      }
    }
#pragma unroll
    for (int d = 1; d <= 2; d <<= 1) {
      float ov = __shfl_xor(wv, d, 64);
      int   ok = __shfl_xor(wk, d, 64);
      if (ov > wv || (ov == wv && ok < wk)) { wv = ov; wk = ok; }
    }
    if (valid && c == 0) {
      int b = pix / (HH * WW);
      int r = pix - b * (HH * WW);
      int y = r / WW, x = r - y * WW;
      int fxi = (b * 2 * HH + y) * WW + x;
      out[fxi] = (float)(wk % 19 - 9);
      out[fxi + HH * WW] = (float)(wk / 19 - 9);
    }
  }

  // deep entries
  for (unsigned d = wid; d < nD; d += nw) {
    uint4 ent = entries[capE - 1 - d];
    unsigned pix = ent.x;
    int b = pix / (HH * WW);
    int r = pix - b * (HH * WW);
    int y = r / WW, x = r - y * WW;
    const float* p1b = p1 + b * HH * WW;
    const float* p2b = p2 + b * HH * WW;
    float wv = -1e30f;
    int   wk = 0x7FFF;
    for (int k = lane; k < 361; k += 64) {
      float s = replay_corr(p1b, p2b, y, x, k);
      if (s > wv || (s == wv && k < wk)) { wv = s; wk = k; }
    }
    for (int off = 32; off > 0; off >>= 1) {
      float ov = __shfl_down(wv, off, 64);
      int   ok = __shfl_down(wk, off, 64);
      if (ov > wv || (ov == wv && ok < wk)) { wv = ov; wk = ok; }
    }
    if (lane == 0) {
      int fxi = (b * 2 * HH + y) * WW + x;
      out[fxi] = (float)(wk % 19 - 9);
      out[fxi + HH * WW] = (float)(wk / 19 - 9);
    }
  }

  // sentinel cleanup — only if the worklist overflowed (normally skipped)
  if (rawN > capHalf || rawD > capHalf) {
    int stride = gridDim.x * blockDim.x;
    for (int idx = blockIdx.x * blockDim.x + threadIdx.x; idx < NPIX;
         idx += stride) {
      int b = idx / (HH * WW);
      int r = idx - b * (HH * WW);
      int fxi = b * 2 * HH * WW + r;
      float fx = out[fxi];
      if (fx < 500000.f) continue;  // not a sentinel
      int fyi = fxi + HH * WW;
      int p = (int)fx - 1000000;
      int q = (int)out[fyi];
      int deep = q >> 18;
      int kk[4] = {p & 511, p >> 9, q & 511, (q >> 9) & 511};
      int y = r / WW, x = r - y * WW;
      const float* p1b = p1 + b * HH * WW;
      const float* p2b = p2 + b * HH * WW;
      float wv = 0.f; int win = -1;
      if (deep) {
        for (int k = 0; k < 361; ++k) {
          float s = replay_corr(p1b, p2b, y, x, k);
          if (win < 0 || s > wv) { wv = s; win = k; }
        }
      } else {
        for (int c = 0; c < 4; ++c) {
          int k = kk[c];
          float s = replay_corr(p1b, p2b, y, x, k);
          if (win < 0 || s > wv || (s == wv && k < win)) { wv = s; win = k; }
        }
      }
      out[fxi] = (float)(win % 19 - 9);
      out[fyi] = (float)(win / 19 - 9);
    }
  }
}

extern "C" void kernel_launch(void* const* d_in, const int* in_sizes, int n_in,
                              void* d_out, int out_size, void* d_ws, size_t ws_size,
                              hipStream_t stream) {
  const float* p1 = (const float*)d_in[0];
  const float* p2 = (const float*)d_in[1];
  float* out = (float*)d_out;
  unsigned* wl = (unsigned*)d_ws;
  unsigned capE = (ws_size >= 64) ? (unsigned)((ws_size - 32) / 16) : 0u;
  hipMemsetAsync(d_ws, 0, 32, stream);  // worklist counters
  dim3 grid1(WW / TW, HH / TH, 4);
  bcm_pass1<<<grid1, dim3(256), 0, stream>>>(p1, p2, out, wl, capE);
  bcm_pass2<<<dim3(512), dim3(256), 0, stream>>>(p1, p2, out, wl, capE);
}